// Round 5
// baseline (730.077 us; speedup 1.0000x reference)
//
#include <hip/hip_runtime.h>
#include <hip/hip_bf16.h>
#include <math.h>

#define Nn 8192
#define Dd 256
#define Uu 128
#define MI 16
#define JS 4
#define JRANGE (Nn / JS)          // 2048
#define NWIN (JRANGE / 64)        // 32 windows per block
#define ZTOT4 ((Nn * Uu + Nn) / 4)

typedef __attribute__((ext_vector_type(4))) float f32x4;
typedef __attribute__((ext_vector_type(8))) short s16x8;
typedef __attribute__((ext_vector_type(4))) short s16x4;

#define MFMA_K32(a, b, c) __builtin_amdgcn_mfma_f32_16x16x32_bf16((a), (b), (c), 0, 0, 0)

#if __has_builtin(__builtin_amdgcn_mfma_f32_16x16x16bf16_1k)
#define MFMA_K16(a, b, c) __builtin_amdgcn_mfma_f32_16x16x16bf16_1k((a), (b), (c), 0, 0, 0)
#elif __has_builtin(__builtin_amdgcn_mfma_f32_16x16x16_bf16)
#define MFMA_K16(a, b, c) __builtin_amdgcn_mfma_f32_16x16x16_bf16((a), (b), (c), 0, 0, 0)
#else
static __device__ __forceinline__ f32x4 mfma_k16_asm(s16x4 a, s16x4 b, f32x4 c){
  asm volatile("v_mfma_f32_16x16x16_bf16 %0, %1, %2, %0" : "+v"(c) : "v"(a), "v"(b));
  return c;
}
#define MFMA_K16(a, b, c) mfma_k16_asm((a), (b), (c))
#endif

__device__ __forceinline__ short f2bf(float f){
  unsigned int u = __float_as_uint(f);
  u += 0x7fffu + ((u >> 16) & 1u);           // RNE
  return (short)(u >> 16);
}

__device__ __forceinline__ float waveSum(float v){
  #pragma unroll
  for (int off = 32; off >= 1; off >>= 1) v += __shfl_xor(v, off);
  return v;
}

// x = expmap0(features @ kernel) -> xh (bf16 [N][U], coalesced), x2 = tanh(|z|)^2.
// Also zeroes the Oacc/lac accumulator region (runs before k_attn on the stream).
__global__ __launch_bounds__(128) void k_prep(const float* __restrict__ feat,
                                              const float* __restrict__ kern,
                                              short* __restrict__ xh,
                                              float* __restrict__ x2,
                                              float4* __restrict__ zreg){
  const int t = threadIdx.x;                  // == u
  const int n0 = blockIdx.x * 16;
  __shared__ float fS[16][Dd];                // 16 KB
  __shared__ float red[2][16];

  // zero accumulator workspace (grid-strided)
  {
    const float4 z4 = {0.f, 0.f, 0.f, 0.f};
    for (int i = blockIdx.x * 128 + t; i < ZTOT4; i += 512 * 128) zreg[i] = z4;
  }

  // stage 16 feat rows (16 KB, coalesced f32x4)
  {
    const f32x4* fg = (const f32x4*)(feat + (size_t)n0 * Dd);
    f32x4* fd = (f32x4*)fS;
    #pragma unroll
    for (int c = 0; c < 8; ++c) fd[c * 128 + t] = fg[c * 128 + t];
  }
  __syncthreads();

  float zz[16];
  #pragma unroll
  for (int r = 0; r < 16; ++r) zz[r] = 0.f;
  for (int dq = 0; dq < 64; ++dq){
    const int d = dq * 4;
    const float k0 = kern[(size_t)(d + 0) * Uu + t];
    const float k1 = kern[(size_t)(d + 1) * Uu + t];
    const float k2 = kern[(size_t)(d + 2) * Uu + t];
    const float k3 = kern[(size_t)(d + 3) * Uu + t];
    #pragma unroll
    for (int r = 0; r < 16; ++r){
      const f32x4 f4 = *(const f32x4*)&fS[r][d];   // broadcast b128, conflict-free
      zz[r] = fmaf(f4.x, k0, fmaf(f4.y, k1, fmaf(f4.z, k2, fmaf(f4.w, k3, zz[r]))));
    }
  }
  #pragma unroll
  for (int r = 0; r < 16; ++r){
    float v = waveSum(zz[r] * zz[r]);
    if ((t & 63) == 0) red[t >> 6][r] = v;
  }
  __syncthreads();
  #pragma unroll
  for (int r = 0; r < 16; ++r){
    const float ns  = red[0][r] + red[1][r];
    const float nrm = fmaxf(sqrtf(ns), 1e-15f);
    const float th  = tanhf(nrm);
    xh[(size_t)(n0 + r) * Uu + t] = f2bf(zz[r] * (th / nrm));
  }
  if (t < 16){
    const float ns  = red[0][t] + red[1][t];
    const float nrm = fmaxf(sqrtf(ns), 1e-15f);
    const float th  = tanhf(nrm);
    x2[n0 + t] = th * th;
  }
}

// xth[u][n] = xh[n][u] via LDS tiles (64n x 64u), fully coalesced both sides
__global__ __launch_bounds__(256) void k_tr(const short* __restrict__ xh,
                                            short* __restrict__ xth){
  const int n0 = (blockIdx.x & 127) * 64;
  const int u0 = (blockIdx.x >> 7) * 64;
  __shared__ short tS[64][72];
  const int r  = threadIdx.x >> 2;
  const int c0 = (threadIdx.x & 3) * 16;
  const short* src = xh + (size_t)(n0 + r) * Uu + u0 + c0;
  *(s16x8*)&tS[r][c0]     = *(const s16x8*)(src);
  *(s16x8*)&tS[r][c0 + 8] = *(const s16x8*)(src + 8);
  __syncthreads();
  s16x8 b0, b1;
  #pragma unroll
  for (int k = 0; k < 8; ++k){ b0[k] = tS[c0 + k][r]; b1[k] = tS[c0 + 8 + k][r]; }
  short* dst = xth + (size_t)(u0 + r) * Nn + n0 + c0;
  *(s16x8*)(dst)     = b0;
  *(s16x8*)(dst + 8) = b1;
}

// b = expmap0(bias); bb[0..127] = b, bb[128] = ||b||^2
__global__ __launch_bounds__(128) void k_bias(const float* __restrict__ bias,
                                              float* __restrict__ bb){
  const int t = threadIdx.x;
  __shared__ float red[2];
  float bv = bias[t];
  float v = waveSum(bv * bv);
  if ((t & 63) == 0) red[t >> 6] = v;
  __syncthreads();
  float n2  = red[0] + red[1];
  float nrm = fmaxf(sqrtf(n2), 1e-15f);
  float th  = tanhf(nrm);
  bb[t] = bv * th / nrm;
  if (t == 0) bb[Uu] = th * th;
}

// Flash over a j-quarter: S^T = K.Q^T -> p = (den+sq)/(den-sq) (== exp(dist), shift-0
// softmax numerator) -> O^T += V^T.P^T. Block combines 4 waves in LDS, then
// atomicAdd partial (l, O) into global accumulators.
__global__ __launch_bounds__(256) void k_attn(const int* __restrict__ adj,
                                              const short* __restrict__ xh,
                                              const short* __restrict__ xth,
                                              const float* __restrict__ x2g,
                                              float* __restrict__ Oacc,
                                              float* __restrict__ lac){
  const int t    = threadIdx.x;
  const int lane = t & 63;
  const int wid  = t >> 6;
  const int l15  = lane & 15;
  const int q4   = lane >> 4;
  const int i0   = (blockIdx.x >> 2) * MI;
  const int jorg = (blockIdx.x & 3) * JRANGE;
  const int irow = i0 + l15;

  __shared__ float oS[4][Uu][17];             // 34 KB
  __shared__ float lS[4][16];

  // Q B-frags in registers for the whole kernel
  s16x8 qf[4];
  {
    const short* qp = xh + (size_t)irow * Uu + q4 * 8;
    #pragma unroll
    for (int kk = 0; kk < 4; ++kk) qf[kk] = *(const s16x8*)(qp + kk * 32);
  }
  const float x2i  = x2g[irow];
  const float Bv   = 1.f - x2i;
  const float Bv2j = Bv * Bv;
  const float nBv2 = -2.f * Bv;

  f32x4 oac[8];
  #pragma unroll
  for (int c = 0; c < 8; ++c) oac[c] = (f32x4){0.f, 0.f, 0.f, 0.f};
  float lacc = 0.f;

#define JW(w) (jorg + (((w) & (NWIN - 1)) << 6) + (wid << 4))
#define LOADA(JWV) (*(const int4*)(adj + (size_t)irow * Nn + (JWV) + q4 * 4))

#define LOADKV(S, JWV) do{                                                     \
    const short* kp_ = xh + (size_t)((JWV) + l15) * Uu + q4 * 8;               \
    kf##S[0] = *(const s16x8*)(kp_);                                           \
    kf##S[1] = *(const s16x8*)(kp_ + 32);                                      \
    kf##S[2] = *(const s16x8*)(kp_ + 64);                                      \
    kf##S[3] = *(const s16x8*)(kp_ + 96);                                      \
    xj##S = *(const f32x4*)(x2g + (JWV) + q4 * 4);                             \
    const short* vp_ = xth + (size_t)l15 * Nn + (JWV) + q4 * 4;                \
    _Pragma("unroll")                                                          \
    for (int c_ = 0; c_ < 8; ++c_)                                             \
      vf##S[c_] = *(const s16x4*)(vp_ + (size_t)c_ * 16 * Nn);                 \
  }while(0)

#define COMPUTE(S, AV, JWV) do{                                                \
    f32x4 s_ = (f32x4){0.f, 0.f, 0.f, 0.f};                                    \
    s_ = MFMA_K32(kf##S[0], qf[0], s_);                                        \
    s_ = MFMA_K32(kf##S[1], qf[1], s_);                                        \
    s_ = MFMA_K32(kf##S[2], qf[2], s_);                                        \
    s_ = MFMA_K32(kf##S[3], qf[3], s_);                                        \
    const int aarr_[4] = {AV.x, AV.y, AV.z, AV.w};                             \
    s16x4 pb_;                                                                 \
    _Pragma("unroll")                                                          \
    for (int r_ = 0; r_ < 4; ++r_){                                            \
      const int   jgl_ = (JWV) + q4 * 4 + r_;                                  \
      const float xy_  = s_[r_];                                               \
      const float x2j_ = xj##S[r_];                                            \
      const float Aa_  = fmaf(-2.f, xy_, 1.f + x2j_);                          \
      const float num_ = fmaf(Aa_ * Aa_, x2i,                                  \
                          fmaf(nBv2 * Aa_, xy_, Bv2j * x2j_));                 \
      const float den_ = fmaf(x2i, x2j_, fmaf(-2.f, xy_, 1.f));                \
      const float sq_  = sqrtf(fmaxf(num_, 0.f));                              \
      const float pd_  = fmaxf(den_ - sq_, 1e-30f);                            \
      float p_ = fminf((den_ + sq_) * __builtin_amdgcn_rcpf(pd_), 2.0e7f);     \
      const bool keep_ = (aarr_[r_] != 0) && (sq_ != 0.f) && (jgl_ != irow);   \
      p_ = keep_ ? p_ : 0.f;                                                   \
      lacc += p_;                                                              \
      pb_[r_] = f2bf(p_);                                                      \
    }                                                                          \
    oac[0] = MFMA_K16(vf##S[0], pb_, oac[0]);                                  \
    oac[1] = MFMA_K16(vf##S[1], pb_, oac[1]);                                  \
    oac[2] = MFMA_K16(vf##S[2], pb_, oac[2]);                                  \
    oac[3] = MFMA_K16(vf##S[3], pb_, oac[3]);                                  \
    oac[4] = MFMA_K16(vf##S[4], pb_, oac[4]);                                  \
    oac[5] = MFMA_K16(vf##S[5], pb_, oac[5]);                                  \
    oac[6] = MFMA_K16(vf##S[6], pb_, oac[6]);                                  \
    oac[7] = MFMA_K16(vf##S[7], pb_, oac[7]);                                  \
  }while(0)

  s16x8 kfA[4]; f32x4 xjA; s16x4 vfA[8];
  s16x8 kfB[4]; f32x4 xjB; s16x4 vfB[8];
  LOADKV(A, JW(0));
  int4 avC = LOADA(JW(0));
  int4 avN = LOADA(JW(1));
  for (int w = 0; w < NWIN; w += 2){
    int4 avF = LOADA(JW(w + 2));            // adj prefetched 2 windows ahead
    LOADKV(B, JW(w + 1));
    COMPUTE(A, avC, JW(w));
    avC = avN; avN = avF;
    avF = LOADA(JW(w + 3));
    LOADKV(A, JW(w + 2));
    COMPUTE(B, avC, JW(w + 1));
    avC = avN; avN = avF;
  }
#undef JW
#undef LOADA
#undef LOADKV
#undef COMPUTE

  // combine 4 waves, then atomically add block partial into global accumulators
  lacc += __shfl_xor(lacc, 16);
  lacc += __shfl_xor(lacc, 32);
  if (lane < 16) lS[wid][lane] = lacc;
  #pragma unroll
  for (int c = 0; c < 8; ++c){
    #pragma unroll
    for (int r = 0; r < 4; ++r)
      oS[wid][c * 16 + q4 * 4 + r][l15] = oac[c][r];
  }
  __syncthreads();

  if (t < 16) atomicAdd(&lac[i0 + t], lS[0][t] + lS[1][t] + lS[2][t] + lS[3][t]);
  const int er = t >> 4;
  const int ec = t & 15;
  #pragma unroll
  for (int k = 0; k < 8; ++k){
    const int u = ec + 16 * k;
    const float v = oS[0][u][er] + oS[1][u][er] + oS[2][u][er] + oS[3][u][er];
    atomicAdd(&Oacc[(size_t)(i0 + er) * Uu + u], v);
  }
}

// epilogue: normalize, mobius matvec rescale, mobius bias add
__global__ __launch_bounds__(256) void k_out(const float* __restrict__ Oacc,
                                             const float* __restrict__ lac,
                                             const float* __restrict__ x2g,
                                             const float* __restrict__ bb,
                                             float* __restrict__ out){
  const int t  = threadIdx.x;
  const int i0 = blockIdx.x * MI;
  const int er = t >> 4;
  const int ec = t & 15;
  const float linv = 1.f / fmaxf(lac[i0 + er], 1e-30f);
  float mx[8]; float s2 = 0.f;
  #pragma unroll
  for (int k = 0; k < 8; ++k){
    float v = Oacc[(size_t)(i0 + er) * Uu + ec + 16 * k] * linv;
    mx[k] = v; s2 = fmaf(v, v, s2);
  }
  s2 += __shfl_xor(s2, 1); s2 += __shfl_xor(s2, 2);
  s2 += __shfl_xor(s2, 4); s2 += __shfl_xor(s2, 8);
  const float mx_n = fmaxf(sqrtf(s2), 1e-15f);
  const float x2e  = x2g[i0 + er];
  const float x_n  = fmaxf(sqrtf(x2e), 1e-15f);
  const float xcl  = fminf(x_n, 1.f - 1e-7f);
  const float art  = 0.5f * __logf((1.f + xcl) / (1.f - xcl));
  const float th   = tanhf(mx_n / x_n * art);
  const float rmn  = th / mx_n;
  float o[8], bu[8]; float ob = 0.f;
  #pragma unroll
  for (int k = 0; k < 8; ++k){
    bu[k] = bb[ec + 16 * k];
    o[k]  = mx[k] * rmn;
    ob = fmaf(o[k], bu[k], ob);
  }
  ob += __shfl_xor(ob, 1); ob += __shfl_xor(ob, 2);
  ob += __shfl_xor(ob, 4); ob += __shfl_xor(ob, 8);
  const float o2   = th * th;
  const float b2   = bb[Uu];
  const float cnum = 1.f + 2.f * ob + b2;
  const float cden = fmaf(o2, b2, 1.f + 2.f * ob);
  const float rden = 1.f / fmaxf(cden, 1e-15f);
  const float co   = 1.f - o2;
  #pragma unroll
  for (int k = 0; k < 8; ++k)
    out[(size_t)(i0 + er) * Uu + ec + 16 * k] = (cnum * o[k] + co * bu[k]) * rden;
}

extern "C" void kernel_launch(void* const* d_in, const int* in_sizes, int n_in,
                              void* d_out, int out_size, void* d_ws, size_t ws_size,
                              hipStream_t stream){
  (void)in_sizes; (void)n_in; (void)out_size; (void)ws_size;
  const float* feat = (const float*)d_in[0];
  const int*   adj  = (const int*)d_in[1];
  const float* kern = (const float*)d_in[2];
  const float* bias = (const float*)d_in[3];

  short* xh   = (short*)d_ws;                      // [N][U] bf16, 2 MB
  short* xth  = xh + (size_t)Nn * Uu;              // [U][N] bf16, 2 MB
  float* Oacc = (float*)(xth + (size_t)Nn * Uu);   // [N][U] f32, 4 MB
  float* lac  = Oacc + (size_t)Nn * Uu;            // [N]
  float* x2   = lac + Nn;                          // [N]
  float* bbw  = x2 + Nn;                           // [U+1]

  k_prep<<<Nn / 16, 128, 0, stream>>>(feat, kern, xh, x2, (float4*)Oacc);
  k_tr  <<<256, 256, 0, stream>>>(xh, xth);
  k_bias<<<1, 128, 0, stream>>>(bias, bbw);
  k_attn<<<(Nn / MI) * JS, 256, 0, stream>>>(adj, xh, xth, x2, Oacc, lac);
  k_out <<<Nn / MI, 256, 0, stream>>>(Oacc, lac, x2, bbw, (float*)d_out);
}

// Round 6
// 629.670 us; speedup vs baseline: 1.1595x; 1.1595x over previous
//
#include <hip/hip_runtime.h>
#include <hip/hip_bf16.h>
#include <math.h>

#define Nn 8192
#define Dd 256
#define Uu 128
#define MI 16
#define JS 2
#define JRANGE (Nn / JS)          // 4096
#define NWIN (JRANGE / 64)        // 64 windows per block
#define ZTOT4 ((Nn * Uu + Nn) / 4)

typedef __attribute__((ext_vector_type(4))) float f32x4;
typedef __attribute__((ext_vector_type(8))) short s16x8;
typedef __attribute__((ext_vector_type(4))) short s16x4;

#define MFMA_K32(a, b, c) __builtin_amdgcn_mfma_f32_16x16x32_bf16((a), (b), (c), 0, 0, 0)

__device__ __forceinline__ short f2bf(float f){
  unsigned int u = __float_as_uint(f);
  u += 0x7fffu + ((u >> 16) & 1u);           // RNE
  return (short)(u >> 16);
}

__device__ __forceinline__ float waveSum(float v){
  #pragma unroll
  for (int off = 32; off >= 1; off >>= 1) v += __shfl_xor(v, off);
  return v;
}

// x = expmap0(features @ kernel) -> xh (bf16 [N][U]), x2 = tanh(|z|)^2; zeroes Oacc+lac
__global__ __launch_bounds__(128) void k_prep(const float* __restrict__ feat,
                                              const float* __restrict__ kern,
                                              short* __restrict__ xh,
                                              float* __restrict__ x2,
                                              float4* __restrict__ zreg){
  const int t = threadIdx.x;                  // == u
  const int n0 = blockIdx.x * 16;
  __shared__ float fS[16][Dd];
  __shared__ float red[2][16];
  {
    const float4 z4 = {0.f, 0.f, 0.f, 0.f};
    for (int i = blockIdx.x * 128 + t; i < ZTOT4; i += 512 * 128) zreg[i] = z4;
  }
  {
    const f32x4* fg = (const f32x4*)(feat + (size_t)n0 * Dd);
    f32x4* fd = (f32x4*)fS;
    #pragma unroll
    for (int c = 0; c < 8; ++c) fd[c * 128 + t] = fg[c * 128 + t];
  }
  __syncthreads();
  float zz[16];
  #pragma unroll
  for (int r = 0; r < 16; ++r) zz[r] = 0.f;
  for (int dq = 0; dq < 64; ++dq){
    const int d = dq * 4;
    const float k0 = kern[(size_t)(d + 0) * Uu + t];
    const float k1 = kern[(size_t)(d + 1) * Uu + t];
    const float k2 = kern[(size_t)(d + 2) * Uu + t];
    const float k3 = kern[(size_t)(d + 3) * Uu + t];
    #pragma unroll
    for (int r = 0; r < 16; ++r){
      const f32x4 f4 = *(const f32x4*)&fS[r][d];
      zz[r] = fmaf(f4.x, k0, fmaf(f4.y, k1, fmaf(f4.z, k2, fmaf(f4.w, k3, zz[r]))));
    }
  }
  #pragma unroll
  for (int r = 0; r < 16; ++r){
    float v = waveSum(zz[r] * zz[r]);
    if ((t & 63) == 0) red[t >> 6][r] = v;
  }
  __syncthreads();
  #pragma unroll
  for (int r = 0; r < 16; ++r){
    const float ns  = red[0][r] + red[1][r];
    const float nrm = fmaxf(sqrtf(ns), 1e-15f);
    const float th  = tanhf(nrm);
    xh[(size_t)(n0 + r) * Uu + t] = f2bf(zz[r] * (th / nrm));
  }
  if (t < 16){
    const float ns  = red[0][t] + red[1][t];
    const float nrm = fmaxf(sqrtf(ns), 1e-15f);
    const float th  = tanhf(nrm);
    x2[n0 + t] = th * th;
  }
}

// xth[u][n] = xh[n][u] via LDS tiles, coalesced both sides
__global__ __launch_bounds__(256) void k_tr(const short* __restrict__ xh,
                                            short* __restrict__ xth){
  const int n0 = (blockIdx.x & 127) * 64;
  const int u0 = (blockIdx.x >> 7) * 64;
  __shared__ short tS[64][72];
  const int r  = threadIdx.x >> 2;
  const int c0 = (threadIdx.x & 3) * 16;
  const short* src = xh + (size_t)(n0 + r) * Uu + u0 + c0;
  *(s16x8*)&tS[r][c0]     = *(const s16x8*)(src);
  *(s16x8*)&tS[r][c0 + 8] = *(const s16x8*)(src + 8);
  __syncthreads();
  s16x8 b0, b1;
  #pragma unroll
  for (int k = 0; k < 8; ++k){ b0[k] = tS[c0 + k][r]; b1[k] = tS[c0 + 8 + k][r]; }
  short* dst = xth + (size_t)(u0 + r) * Nn + n0 + c0;
  *(s16x8*)(dst)     = b0;
  *(s16x8*)(dst + 8) = b1;
}

__global__ __launch_bounds__(128) void k_bias(const float* __restrict__ bias,
                                              float* __restrict__ bb){
  const int t = threadIdx.x;
  __shared__ float red[2];
  float bv = bias[t];
  float v = waveSum(bv * bv);
  if ((t & 63) == 0) red[t >> 6] = v;
  __syncthreads();
  float n2  = red[0] + red[1];
  float nrm = fmaxf(sqrtf(n2), 1e-15f);
  float th  = tanhf(nrm);
  bb[t] = bv * th / nrm;
  if (t == 0) bb[Uu] = th * th;
}

// Flash window loop: wave w computes S^T for its 16-j slice (K gather + 4 K32 MFMA),
// p = (den+sq)/(den-sq) == exp(dist), writes bf16 P^T tile to LDS (dbuf, 1 barrier),
// then contracts the FULL 64-j window into its private 32-u O^T chunk (4 K32 MFMA,
// V^T A-frags = contiguous b128 global loads). Registers: 8 acc, no cross-wave combine.
__global__ __launch_bounds__(256, 4) void k_attn(const int* __restrict__ adj,
                                                 const short* __restrict__ xh,
                                                 const short* __restrict__ xth,
                                                 const float* __restrict__ x2g,
                                                 float* __restrict__ Oacc,
                                                 float* __restrict__ lac){
  const int t    = threadIdx.x;
  const int lane = t & 63;
  const int wid  = t >> 6;
  const int l15  = lane & 15;
  const int q4   = lane >> 4;
  const int i0   = (blockIdx.x >> 1) * MI;
  const int jorg = (blockIdx.x & 1) * JRANGE;
  const int irow = i0 + l15;

  __shared__ short Pt[2][MI][72];             // 4.5 KB, padded (2-way max)
  __shared__ float oPark[MI][132];            // 8.25 KB, epilogue only

  // Q B-frags in registers for the whole kernel
  s16x8 qf[4];
  {
    const short* qp = xh + (size_t)irow * Uu + q4 * 8;
    #pragma unroll
    for (int kk = 0; kk < 4; ++kk) qf[kk] = *(const s16x8*)(qp + kk * 32);
  }
  const float x2i  = x2g[irow];
  const float Bv   = 1.f - x2i;
  const float Bv2j = Bv * Bv;
  const float nBv2 = -2.f * Bv;

  f32x4 oac0 = {0.f, 0.f, 0.f, 0.f};
  f32x4 oac1 = {0.f, 0.f, 0.f, 0.f};
  float lacc = 0.f;

#define JSL(w) (jorg + (((w) & (NWIN - 1)) << 6) + (wid << 4))

  s16x8 kfC[4], kfN[4];
  f32x4 xjC, xjN;
  int4 aq0, aq1;
  {
    const short* kp = xh + (size_t)(JSL(0) + l15) * Uu + q4 * 8;
    #pragma unroll
    for (int kk = 0; kk < 4; ++kk) kfC[kk] = *(const s16x8*)(kp + kk * 32);
    xjC = *(const f32x4*)(x2g + JSL(0) + q4 * 4);
  }
  aq0 = *(const int4*)(adj + (size_t)irow * Nn + JSL(0) + q4 * 4);
  aq1 = *(const int4*)(adj + (size_t)irow * Nn + JSL(1) + q4 * 4);

  for (int w = 0; w < NWIN; ++w){
    const int jsl = JSL(w);
    const int jw  = jorg + (w << 6);
    // prefetch next kf / x2j
    {
      const short* kp = xh + (size_t)(JSL(w + 1) + l15) * Uu + q4 * 8;
      #pragma unroll
      for (int kk = 0; kk < 4; ++kk) kfN[kk] = *(const s16x8*)(kp + kk * 32);
      xjN = *(const f32x4*)(x2g + JSL(w + 1) + q4 * 4);
    }
    // V^T A-frags for current window (contiguous 16B/lane)
    s16x8 vf00, vf01, vf10, vf11;
    {
      const short* vp0 = xth + (size_t)(wid * 32 + l15) * Nn + jw + q4 * 8;
      const short* vp1 = xth + (size_t)(wid * 32 + 16 + l15) * Nn + jw + q4 * 8;
      vf00 = *(const s16x8*)(vp0);
      vf01 = *(const s16x8*)(vp0 + 32);
      vf10 = *(const s16x8*)(vp1);
      vf11 = *(const s16x8*)(vp1 + 32);
    }
    // adj prefetch 2 windows ahead
    const int4 aqN = *(const int4*)(adj + (size_t)irow * Nn + JSL(w + 2) + q4 * 4);

    // ---- S^T slice: 4 MFMA ----
    f32x4 s = {0.f, 0.f, 0.f, 0.f};
    s = MFMA_K32(kfC[0], qf[0], s);
    s = MFMA_K32(kfC[1], qf[1], s);
    s = MFMA_K32(kfC[2], qf[2], s);
    s = MFMA_K32(kfC[3], qf[3], s);

    // ---- dist -> p (exp(dist) closed form), mask, pack ----
    const int aarr[4] = {aq0.x, aq0.y, aq0.z, aq0.w};
    s16x4 pb;
    #pragma unroll
    for (int r = 0; r < 4; ++r){
      const int   jgl = jsl + q4 * 4 + r;
      const float xy  = s[r];
      const float x2j = xjC[r];
      const float Aa  = fmaf(-2.f, xy, 1.f + x2j);
      const float num = fmaf(Aa * Aa, x2i, fmaf(nBv2 * Aa, xy, Bv2j * x2j));
      const float den = fmaf(x2i, x2j, fmaf(-2.f, xy, 1.f));
      const float sq  = sqrtf(fmaxf(num, 0.f));
      const float pd  = fmaxf(den - sq, 1e-30f);
      float p = fminf((den + sq) * __builtin_amdgcn_rcpf(pd), 2.0e7f);
      const bool keep = (aarr[r] != 0) && (sq != 0.f) && (jgl != irow);
      p = keep ? p : 0.f;
      lacc += p;
      pb[r] = f2bf(p);
    }
    *(s16x4*)&Pt[w & 1][l15][wid * 16 + q4 * 4] = pb;
    __syncthreads();

    // ---- O^T += V^T . P^T over full 64-j window (wave-private 32-u chunk) ----
    {
      const short* pr = &Pt[w & 1][l15][0];
      const s16x8 bf0 = *(const s16x8*)(pr + q4 * 8);
      const s16x8 bf1 = *(const s16x8*)(pr + 32 + q4 * 8);
      oac0 = MFMA_K32(vf00, bf0, oac0);
      oac0 = MFMA_K32(vf01, bf1, oac0);
      oac1 = MFMA_K32(vf10, bf0, oac1);
      oac1 = MFMA_K32(vf11, bf1, oac1);
    }
    // rotate prefetch
    #pragma unroll
    for (int kk = 0; kk < 4; ++kk) kfC[kk] = kfN[kk];
    xjC = xjN;
    aq0 = aq1; aq1 = aqN;
  }
#undef JSL

  // ---- epilogue: l reduce, park O^T -> coalesced atomic add ----
  lacc += __shfl_xor(lacc, 16);
  lacc += __shfl_xor(lacc, 32);
  if (lane < 16) atomicAdd(&lac[i0 + lane], lacc);
  #pragma unroll
  for (int r = 0; r < 4; ++r){
    oPark[l15][wid * 32 + q4 * 4 + r]      = oac0[r];
    oPark[l15][wid * 32 + 16 + q4 * 4 + r] = oac1[r];
  }
  __syncthreads();
  const int er = t >> 4;
  const int ec = t & 15;
  float* dst = Oacc + (size_t)(i0 + er) * Uu + ec * 8;
  #pragma unroll
  for (int k = 0; k < 8; ++k) atomicAdd(dst + k, oPark[er][ec * 8 + k]);
}

// epilogue: normalize, mobius matvec rescale, mobius bias add
__global__ __launch_bounds__(256) void k_out(const float* __restrict__ Oacc,
                                             const float* __restrict__ lac,
                                             const float* __restrict__ x2g,
                                             const float* __restrict__ bb,
                                             float* __restrict__ out){
  const int t  = threadIdx.x;
  const int i0 = blockIdx.x * MI;
  const int er = t >> 4;
  const int ec = t & 15;
  const float linv = 1.f / fmaxf(lac[i0 + er], 1e-30f);
  float mx[8]; float s2 = 0.f;
  #pragma unroll
  for (int k = 0; k < 8; ++k){
    float v = Oacc[(size_t)(i0 + er) * Uu + ec + 16 * k] * linv;
    mx[k] = v; s2 = fmaf(v, v, s2);
  }
  s2 += __shfl_xor(s2, 1); s2 += __shfl_xor(s2, 2);
  s2 += __shfl_xor(s2, 4); s2 += __shfl_xor(s2, 8);
  const float mx_n = fmaxf(sqrtf(s2), 1e-15f);
  const float x2e  = x2g[i0 + er];
  const float x_n  = fmaxf(sqrtf(x2e), 1e-15f);
  const float xcl  = fminf(x_n, 1.f - 1e-7f);
  const float art  = 0.5f * __logf((1.f + xcl) / (1.f - xcl));
  const float th   = tanhf(mx_n / x_n * art);
  const float rmn  = th / mx_n;
  float o[8], bu[8]; float ob = 0.f;
  #pragma unroll
  for (int k = 0; k < 8; ++k){
    bu[k] = bb[ec + 16 * k];
    o[k]  = mx[k] * rmn;
    ob = fmaf(o[k], bu[k], ob);
  }
  ob += __shfl_xor(ob, 1); ob += __shfl_xor(ob, 2);
  ob += __shfl_xor(ob, 4); ob += __shfl_xor(ob, 8);
  const float o2   = th * th;
  const float b2   = bb[Uu];
  const float cnum = 1.f + 2.f * ob + b2;
  const float cden = fmaf(o2, b2, 1.f + 2.f * ob);
  const float rden = 1.f / fmaxf(cden, 1e-15f);
  const float co   = 1.f - o2;
  #pragma unroll
  for (int k = 0; k < 8; ++k)
    out[(size_t)(i0 + er) * Uu + ec + 16 * k] = (cnum * o[k] + co * bu[k]) * rden;
}

extern "C" void kernel_launch(void* const* d_in, const int* in_sizes, int n_in,
                              void* d_out, int out_size, void* d_ws, size_t ws_size,
                              hipStream_t stream){
  (void)in_sizes; (void)n_in; (void)out_size; (void)ws_size;
  const float* feat = (const float*)d_in[0];
  const int*   adj  = (const int*)d_in[1];
  const float* kern = (const float*)d_in[2];
  const float* bias = (const float*)d_in[3];

  short* xh   = (short*)d_ws;                      // [N][U] bf16, 2 MB
  short* xth  = xh + (size_t)Nn * Uu;              // [U][N] bf16, 2 MB
  float* Oacc = (float*)(xth + (size_t)Nn * Uu);   // [N][U] f32, 4 MB
  float* lac  = Oacc + (size_t)Nn * Uu;            // [N]
  float* x2   = lac + Nn;                          // [N]
  float* bbw  = x2 + Nn;                           // [U+1]

  k_prep<<<Nn / 16, 128, 0, stream>>>(feat, kern, xh, x2, (float4*)Oacc);
  k_tr  <<<256, 256, 0, stream>>>(xh, xth);
  k_bias<<<1, 128, 0, stream>>>(bias, bbw);
  k_attn<<<(Nn / MI) * JS, 256, 0, stream>>>(adj, xh, xth, x2, Oacc, lac);
  k_out <<<Nn / MI, 256, 0, stream>>>(Oacc, lac, x2, bbw, (float*)d_out);
}